// Round 13
// baseline (28.800 us; speedup 1.0000x reference)
//
#include <hip/hip_runtime.h>

#define B_ROWS   32768
#define NUM_CLS  1000
#define FEAT     512

#define INTER_BLOCKS    16
#define INTRA_BLOCKS    1024
#define TOTAL_BLOCKS    (INTER_BLOCKS + INTRA_BLOCKS)   // 1040
#define THREADS         256
#define WAVES_PER_BLOCK 4
#define ROWS_PER_WAVE   8      // 1024 * 4 * 8 = 32768
#define LABELS_PER_IB   (B_ROWS / INTER_BLOCKS)         // 2048
#define LISTCAP         128

typedef float f32x4 __attribute__((ext_vector_type(4)));
typedef float f32x2 __attribute__((ext_vector_type(2)));

// ws layout (floats) — all cross-block slots written via agent-scope atomics
// unconditionally every call (overwrite), so no zeroing is ever needed:
//   [0 .. 1024)               intra per-BLOCK partials
//   [1024 .. 1024+16*1032)    inter per-block slots:
//       slot+0 = cnt0, slot+1 = cnt1, slot+[2..514) = sum0, slot+[514..1026) = sum1
//   [17536 .. 17538)          64-bit monotonic done counter (never reset; mod-1040 winner)
#define WS_INTRA 0
#define WS_INTER 1024
#define SLOT     1032
#define WS_DONE  17536

#define ASTORE(p, v) __hip_atomic_store((p), (v), __ATOMIC_RELAXED, __HIP_MEMORY_SCOPE_AGENT)
#define ALOAD(p)     __hip_atomic_load((p), __ATOMIC_RELAXED, __HIP_MEMORY_SCOPE_AGENT)

// issue feature+center loads for rows ROW, ROW+1 into 8 named f32x4 regs
#define LOADPAIR(ROW, FA,FB,FC,FD, CA,CB,CC,CD) do {                         \
    const int _lab0 = labels[(ROW)];                                         \
    const int _lab1 = labels[(ROW) + 1];                                     \
    const f32x4* _f0 = (const f32x4*)(features + (size_t)(ROW) * FEAT);      \
    const f32x4* _f1 = (const f32x4*)(features + (size_t)((ROW)+1) * FEAT);  \
    const f32x4* _c0 = (const f32x4*)(center + (size_t)_lab0 * FEAT);        \
    const f32x4* _c1 = (const f32x4*)(center + (size_t)_lab1 * FEAT);        \
    FA = _f0[lane]; FB = _f0[lane + 64];                                     \
    FC = _f1[lane]; FD = _f1[lane + 64];                                     \
    CA = _c0[lane]; CB = _c0[lane + 64];                                     \
    CC = _c1[lane]; CD = _c1[lane + 64];                                     \
} while (0)

// reduce a 2-row stage to the pair's distance sum (uniform across lanes)
#define REDUCE2(FA,FB,FC,FD, CA,CB,CC,CD) ({                                 \
    f32x4 _d0 = FA - CA, _d1 = FB - CB, _d2 = FC - CC, _d3 = FD - CD;        \
    float _p0 = _d0.x*_d0.x + _d0.y*_d0.y + _d0.z*_d0.z + _d0.w*_d0.w        \
              + _d1.x*_d1.x + _d1.y*_d1.y + _d1.z*_d1.z + _d1.w*_d1.w;       \
    float _p1 = _d2.x*_d2.x + _d2.y*_d2.y + _d2.z*_d2.z + _d2.w*_d2.w        \
              + _d3.x*_d3.x + _d3.y*_d3.y + _d3.z*_d3.z + _d3.w*_d3.w;       \
    const bool _b0 = lane & 1;                                               \
    float _send = _b0 ? _p0 : _p1;                                           \
    float _keep = _b0 ? _p1 : _p0;                                           \
    float _u = _keep + __shfl_xor(_send, 1);                                 \
    _u += __shfl_xor(_u, 2);                                                 \
    _u += __shfl_xor(_u, 4);                                                 \
    _u += __shfl_xor(_u, 8);                                                 \
    _u += __shfl_xor(_u, 16);                                                \
    _u += __shfl_xor(_u, 32);                                                \
    float _dist = sqrtf(_u);                                                 \
    _dist = fminf(fmaxf(_dist, 1e-12f), 1e12f);                              \
    _dist + __shfl_xor(_dist, 1);                                            \
})

__global__ __launch_bounds__(THREADS, 4) void loss_one(
    const float* __restrict__ features,
    const int*   __restrict__ labels,
    const float* __restrict__ center,
    float*       __restrict__ ws,
    float*       __restrict__ out)
{
    const int t    = threadIdx.x;
    const int lane = t & 63;

    if (blockIdx.x < INTER_BLOCKS) {
        // ================= inter blocks: class C-2/C-1 partial sums =================
        const int ib = blockIdx.x;

        __shared__ int list[LISTCAP];
        __shared__ int nm_s;
        if (t == 0) nm_s = 0;
        __syncthreads();

        const int4* lab4 = (const int4*)(labels + ib * LABELS_PER_IB);
        #pragma unroll
        for (int k = 0; k < 2; ++k) {
            const int j = t + k * 256;
            int4 L = lab4[j];
            const int row0 = ib * LABELS_PER_IB + 4 * j;
            if (L.x >= NUM_CLS - 2) { int i = atomicAdd(&nm_s, 1); if (i < LISTCAP) list[i] = (row0 << 1)       | (L.x - (NUM_CLS - 2)); }
            if (L.y >= NUM_CLS - 2) { int i = atomicAdd(&nm_s, 1); if (i < LISTCAP) list[i] = ((row0 + 1) << 1) | (L.y - (NUM_CLS - 2)); }
            if (L.z >= NUM_CLS - 2) { int i = atomicAdd(&nm_s, 1); if (i < LISTCAP) list[i] = ((row0 + 2) << 1) | (L.z - (NUM_CLS - 2)); }
            if (L.w >= NUM_CLS - 2) { int i = atomicAdd(&nm_s, 1); if (i < LISTCAP) list[i] = ((row0 + 3) << 1) | (L.w - (NUM_CLS - 2)); }
        }
        __syncthreads();
        const int nm = min(nm_s, LISTCAP);

        float s0a = 0.0f, s0b = 0.0f, s1a = 0.0f, s1b = 0.0f;
        int c0 = 0, c1 = 0;
        for (int m = 0; m < nm; ++m) {
            const int e   = list[m];
            const int row = e >> 1;
            const f32x2 v = ((const f32x2*)(features + (size_t)row * FEAT))[t];
            if (e & 1) { s1a += v.x; s1b += v.y; ++c1; }
            else       { s0a += v.x; s0b += v.y; ++c0; }
        }

        float* slot = ws + WS_INTER + ib * SLOT;
        if (t == 0) { ASTORE(&slot[0], (float)c0); ASTORE(&slot[1], (float)c1); }
        ASTORE(&slot[2 + 2*t],       s0a);
        ASTORE(&slot[2 + 2*t + 1],   s0b);
        ASTORE(&slot[514 + 2*t],     s1a);
        ASTORE(&slot[514 + 2*t + 1], s1b);
    } else {
        // ===== intra blocks: 8 rows/wave, 2-deep pipelined streaming reduce =====
        const int bid  = blockIdx.x - INTER_BLOCKS;
        const int wave = __builtin_amdgcn_readfirstlane(t >> 6);
        const int wid  = bid * WAVES_PER_BLOCK + wave;
        const int base_row = wid * ROWS_PER_WAVE;

        f32x4 fa0, fb0, fc0, fd0, ca0, cb0, cc0, cd0;
        f32x4 fa1, fb1, fc1, fd1, ca1, cb1, cc1, cd1;
        float acc;

        LOADPAIR(base_row,     fa0, fb0, fc0, fd0, ca0, cb0, cc0, cd0);
        LOADPAIR(base_row + 2, fa1, fb1, fc1, fd1, ca1, cb1, cc1, cd1);
        acc  = REDUCE2(fa0, fb0, fc0, fd0, ca0, cb0, cc0, cd0);
        LOADPAIR(base_row + 4, fa0, fb0, fc0, fd0, ca0, cb0, cc0, cd0);
        acc += REDUCE2(fa1, fb1, fc1, fd1, ca1, cb1, cc1, cd1);
        LOADPAIR(base_row + 6, fa1, fb1, fc1, fd1, ca1, cb1, cc1, cd1);
        acc += REDUCE2(fa0, fb0, fc0, fd0, ca0, cb0, cc0, cd0);
        acc += REDUCE2(fa1, fb1, fc1, fd1, ca1, cb1, cc1, cd1);

        __shared__ float s[WAVES_PER_BLOCK];
        if (lane == 0) s[wave] = acc;
        __syncthreads();
        if (t == 0)
            ASTORE(&ws[WS_INTRA + bid], s[0] + s[1] + s[2] + s[3]);
    }

    // ======== join: ensure this block's atomic stores reached the coherent point ========
    asm volatile("s_waitcnt vmcnt(0)" ::: "memory");
    __syncthreads();

    __shared__ int winner_s;
    if (t == 0) {
        unsigned long long* done = (unsigned long long*)(ws + WS_DONE);
        unsigned long long old = __hip_atomic_fetch_add(done, 1ULL, __ATOMIC_RELAXED,
                                                        __HIP_MEMORY_SCOPE_AGENT);
        winner_s = ((old % (unsigned long long)TOTAL_BLOCKS) ==
                    (unsigned long long)(TOTAL_BLOCKS - 1)) ? 1 : 0;
    }
    __syncthreads();
    if (!winner_s) return;

    // ======== winner block: final reduction (all data read via L2-bypass atomics) ========
    // intra: 1024 block partials, 4 per thread
    float p_intra = 0.0f;
    #pragma unroll
    for (int k = 0; k < 4; ++k)
        p_intra += ALOAD(&ws[WS_INTRA + t + k * 256]);

    // counts (uniform broadcast loads)
    float cnt0 = 0.0f, cnt1 = 0.0f;
    #pragma unroll
    for (int b = 0; b < INTER_BLOCKS; ++b) {
        const float* slot = ws + WS_INTER + b * SLOT;
        cnt0 += ALOAD(&slot[0]);
        cnt1 += ALOAD(&slot[1]);
    }
    cnt0 = fmaxf(cnt0, 1.0f);
    cnt1 = fmaxf(cnt1, 1.0f);

    // class sums: thread t owns dims 2t, 2t+1
    float s0a = 0.0f, s0b = 0.0f, s1a = 0.0f, s1b = 0.0f;
    #pragma unroll
    for (int b = 0; b < INTER_BLOCKS; ++b) {
        const float* slot = ws + WS_INTER + b * SLOT;
        s0a += ALOAD(&slot[2 + 2*t]);
        s0b += ALOAD(&slot[2 + 2*t + 1]);
        s1a += ALOAD(&slot[514 + 2*t]);
        s1b += ALOAD(&slot[514 + 2*t + 1]);
    }

    const int d = 2 * t;
    float a0 = (center[(size_t)(NUM_CLS - 2) * FEAT + d]     + s0a) / cnt0;
    float b0 = (center[(size_t)(NUM_CLS - 1) * FEAT + d]     + s1a) / cnt1;
    float a1 = (center[(size_t)(NUM_CLS - 2) * FEAT + d + 1] + s0b) / cnt0;
    float b1 = (center[(size_t)(NUM_CLS - 1) * FEAT + d + 1] + s1b) / cnt1;
    float df0 = a0 - b0, df1 = a1 - b1;
    float p_inter = df0 * df0 + df1 * df1;

    #pragma unroll
    for (int off = 32; off; off >>= 1) {
        p_inter += __shfl_xor(p_inter, off);
        p_intra += __shfl_xor(p_intra, off);
    }

    __shared__ float si[4], sa[4];
    if (lane == 0) { si[t >> 6] = p_inter; sa[t >> 6] = p_intra; }
    __syncthreads();

    if (t == 0) {
        float d_last = sqrtf(si[0] + si[1] + si[2] + si[3]);
        out[0] = (sa[0] + sa[1] + sa[2] + sa[3]) * (1.0f / (float)B_ROWS);
        out[1] = (2.0f / d_last) * (1.0f / ((float)NUM_CLS * (float)(NUM_CLS - 1)));
    }
}

extern "C" void kernel_launch(void* const* d_in, const int* in_sizes, int n_in,
                              void* d_out, int out_size, void* d_ws, size_t ws_size,
                              hipStream_t stream) {
    const float* features = (const float*)d_in[0];
    const int*   labels   = (const int*)d_in[1];
    const float* center   = (const float*)d_in[2];
    float* out = (float*)d_out;
    float* ws  = (float*)d_ws;

    loss_one<<<TOTAL_BLOCKS, THREADS, 0, stream>>>(features, labels, center, ws, out);
}

// Round 14
// 21.374 us; speedup vs baseline: 1.3474x; 1.3474x over previous
//
#include <hip/hip_runtime.h>

#define B_ROWS   32768
#define NUM_CLS  1000
#define FEAT     512

#define INTER_BLOCKS    16
#define INTRA_BLOCKS    4096
#define THREADS         256
#define WAVES_PER_BLOCK 4
#define ROWS_PER_WAVE   2      // 4096 * 4 * 2 = 32768
#define TOTAL_WAVES     (INTRA_BLOCKS * WAVES_PER_BLOCK)   // 16384
#define LABELS_PER_IB   (B_ROWS / INTER_BLOCKS)   // 2048
#define LISTCAP         128

typedef float f32x4 __attribute__((ext_vector_type(4)));
typedef float f32x2 __attribute__((ext_vector_type(2)));

// ws layout (floats) — every slot written unconditionally every call, no zeroing:
//   [0 .. 16384)                per-WAVE intra partials
//   [16384 .. 16384+16*1032)    inter per-block slots:
//       slot+0 = cnt0, slot+1 = cnt1, slot+[2..514) = sum0, slot+[514..1026) = sum1
#define WS_INTER 16384
#define SLOT     1032

__global__ __launch_bounds__(THREADS, 8) void loss_pass1(
    const float* __restrict__ features,
    const int*   __restrict__ labels,
    const float* __restrict__ center,
    float*       __restrict__ ws)
{
    if (blockIdx.x < INTER_BLOCKS) {
        // ================= inter blocks: class C-2/C-1 partial sums =================
        const int ib = blockIdx.x;
        const int t  = threadIdx.x;

        __shared__ int list[LISTCAP];
        __shared__ int nm_s;
        if (t == 0) nm_s = 0;
        __syncthreads();

        const int4* lab4 = (const int4*)(labels + ib * LABELS_PER_IB);
        #pragma unroll
        for (int k = 0; k < 2; ++k) {
            const int j = t + k * 256;
            int4 L = lab4[j];
            const int row0 = ib * LABELS_PER_IB + 4 * j;
            if (L.x >= NUM_CLS - 2) { int i = atomicAdd(&nm_s, 1); if (i < LISTCAP) list[i] = (row0 << 1)       | (L.x - (NUM_CLS - 2)); }
            if (L.y >= NUM_CLS - 2) { int i = atomicAdd(&nm_s, 1); if (i < LISTCAP) list[i] = ((row0 + 1) << 1) | (L.y - (NUM_CLS - 2)); }
            if (L.z >= NUM_CLS - 2) { int i = atomicAdd(&nm_s, 1); if (i < LISTCAP) list[i] = ((row0 + 2) << 1) | (L.z - (NUM_CLS - 2)); }
            if (L.w >= NUM_CLS - 2) { int i = atomicAdd(&nm_s, 1); if (i < LISTCAP) list[i] = ((row0 + 3) << 1) | (L.w - (NUM_CLS - 2)); }
        }
        __syncthreads();
        const int nm = min(nm_s, LISTCAP);

        float s0a = 0.0f, s0b = 0.0f, s1a = 0.0f, s1b = 0.0f;
        int c0 = 0, c1 = 0;
        for (int m = 0; m < nm; ++m) {
            const int e   = list[m];
            const int row = e >> 1;
            const f32x2 v = ((const f32x2*)(features + (size_t)row * FEAT))[t];
            if (e & 1) { s1a += v.x; s1b += v.y; ++c1; }
            else       { s0a += v.x; s0b += v.y; ++c0; }
        }

        float* slot = ws + WS_INTER + ib * SLOT;
        if (t == 0) { slot[0] = (float)c0; slot[1] = (float)c1; }
        f32x2 v0; v0.x = s0a; v0.y = s0b;
        f32x2 v1; v1.x = s1a; v1.y = s1b;
        ((f32x2*)(slot + 2))[t]   = v0;
        ((f32x2*)(slot + 514))[t] = v1;
        return;
    }

    // ================= intra blocks: streaming distance reduce =================
    const int bid  = blockIdx.x - INTER_BLOCKS;
    const int lane = threadIdx.x & 63;
    // wave id, forced wave-uniform into an SGPR
    const int wave = __builtin_amdgcn_readfirstlane(threadIdx.x >> 6);
    const int wid  = bid * WAVES_PER_BLOCK + wave;
    const int base_row = wid * ROWS_PER_WAVE;

    // wave-uniform scalar label loads (SMEM path, no vector round-trip + shfl)
    const int lab0 = labels[base_row];
    const int lab1 = labels[base_row + 1];

    const f32x4* f0p = (const f32x4*)(features + (size_t)base_row * FEAT);
    const f32x4* f1p = (const f32x4*)(features + (size_t)(base_row + 1) * FEAT);
    const f32x4* c0p = (const f32x4*)(center   + (size_t)lab0 * FEAT);
    const f32x4* c1p = (const f32x4*)(center   + (size_t)lab1 * FEAT);

    f32x4 fa = f0p[lane];
    f32x4 fb = f0p[lane + 64];
    f32x4 fc = f1p[lane];
    f32x4 fd = f1p[lane + 64];
    f32x4 ca = c0p[lane];
    f32x4 cb = c0p[lane + 64];
    f32x4 cc = c1p[lane];
    f32x4 cd = c1p[lane + 64];

    f32x4 d0 = fa - ca, d1 = fb - cb, d2 = fc - cc, d3 = fd - cd;
    float p0 = d0.x*d0.x + d0.y*d0.y + d0.z*d0.z + d0.w*d0.w
             + d1.x*d1.x + d1.y*d1.y + d1.z*d1.z + d1.w*d1.w;
    float p1 = d2.x*d2.x + d2.y*d2.y + d2.z*d2.z + d2.w*d2.w
             + d3.x*d3.x + d3.y*d3.y + d3.z*d3.z + d3.w*d3.w;

    // 2 row-sums across 64 lanes in 7 shuffles
    const bool b0 = lane & 1;
    float send = b0 ? p0 : p1;
    float keep = b0 ? p1 : p0;
    float u = keep + __shfl_xor(send, 1);
    u += __shfl_xor(u, 2);
    u += __shfl_xor(u, 4);
    u += __shfl_xor(u, 8);
    u += __shfl_xor(u, 16);
    u += __shfl_xor(u, 32);
    float dist = sqrtf(u);
    dist = fminf(fmaxf(dist, 1e-12f), 1e12f);
    dist += __shfl_xor(dist, 1);            // sum the 2 rows

    if (lane == 0)
        ws[wid] = dist;    // unique per-wave slot: no LDS, no barrier, no atomic
}

__global__ __launch_bounds__(512) void loss_pass2(
    const float* __restrict__ center,
    const float* __restrict__ ws,
    float*       __restrict__ out)
{
    const int t = threadIdx.x;     // 512 threads, 8 waves

    // counts (wave-uniform broadcast loads)
    float cnt0 = 0.0f, cnt1 = 0.0f;
    #pragma unroll
    for (int b = 0; b < INTER_BLOCKS; ++b) {
        const float* slot = ws + WS_INTER + b * SLOT;
        cnt0 += slot[0];
        cnt1 += slot[1];
    }
    cnt0 = fmaxf(cnt0, 1.0f);
    cnt1 = fmaxf(cnt1, 1.0f);

    // class sums: thread t owns dim t
    float s0 = 0.0f, s1 = 0.0f;
    #pragma unroll
    for (int b = 0; b < INTER_BLOCKS; ++b) {
        const float* slot = ws + WS_INTER + b * SLOT;
        s0 += slot[2 + t];
        s1 += slot[514 + t];
    }

    float a  = (center[(size_t)(NUM_CLS - 2) * FEAT + t] + s0) / cnt0;
    float bb = (center[(size_t)(NUM_CLS - 1) * FEAT + t] + s1) / cnt1;
    float df = a - bb;
    float p_inter = df * df;

    // intra: 16384 wave partials, f32x4 x 8 per thread
    const f32x4* part4 = (const f32x4*)ws;
    float p_intra = 0.0f;
    #pragma unroll
    for (int k = 0; k < 8; ++k) {
        f32x4 v = part4[t + k * 512];
        p_intra += (v.x + v.y) + (v.z + v.w);
    }

    #pragma unroll
    for (int off = 32; off; off >>= 1) {
        p_inter += __shfl_xor(p_inter, off);
        p_intra += __shfl_xor(p_intra, off);
    }

    __shared__ float si[8], sa[8];
    if ((t & 63) == 0) { si[t >> 6] = p_inter; sa[t >> 6] = p_intra; }
    __syncthreads();

    if (t == 0) {
        float s_inter = 0.0f, s_intra = 0.0f;
        #pragma unroll
        for (int i = 0; i < 8; ++i) { s_inter += si[i]; s_intra += sa[i]; }
        float d_last = sqrtf(s_inter);
        out[0] = s_intra * (1.0f / (float)B_ROWS);
        out[1] = (2.0f / d_last) * (1.0f / ((float)NUM_CLS * (float)(NUM_CLS - 1)));
    }
}

extern "C" void kernel_launch(void* const* d_in, const int* in_sizes, int n_in,
                              void* d_out, int out_size, void* d_ws, size_t ws_size,
                              hipStream_t stream) {
    const float* features = (const float*)d_in[0];
    const int*   labels   = (const int*)d_in[1];
    const float* center   = (const float*)d_in[2];
    float* out = (float*)d_out;
    float* ws  = (float*)d_ws;

    loss_pass1<<<INTER_BLOCKS + INTRA_BLOCKS, THREADS, 0, stream>>>(features, labels, center, ws);
    loss_pass2<<<1, 512, 0, stream>>>(center, ws, out);
}